// Round 5
// baseline (566.714 us; speedup 1.0000x reference)
//
#include <hip/hip_runtime.h>

#define NPTS 65536
#define INC  256
#define MID  64
#define KNB  16
#define WSTR 72   // padded LDS row stride (shorts)

// fragment-buffer offsets in shorts (workspace, written by k_prep)
#define WIN_S   0        // w_in   2048 entries
#define WQ_S    16384    // w_q     512
#define WK_S    20480    // w_k     512
#define WV_S    24576    // w_v     512
#define GA1_S   28672    // ga_w1   512
#define GA2_S   32768    // ga_w2   512
#define WOUT_S  36864    // w_out  2048
#define NFRAG_ENT 6656

typedef __attribute__((ext_vector_type(8))) short short8;
typedef __attribute__((ext_vector_type(4))) float f32x4;

#define MFMA(a, b, c) __builtin_amdgcn_mfma_f32_16x16x32_bf16((a), (b), (c), 0, 0, 0)

__device__ inline short f2bf(float f) {
    unsigned int u = __builtin_bit_cast(unsigned int, f);
    unsigned int r = (u + 0x7fffu + ((u >> 16) & 1u)) >> 16;
    return (short)r;
}
__device__ inline float bf2f(unsigned short s) {
    unsigned int u = ((unsigned int)s) << 16;
    return __builtin_bit_cast(float, u);
}
__device__ inline short8 cvtf8(f32x4 a, f32x4 b) {
    short8 r;
    r[0] = f2bf(a[0]); r[1] = f2bf(a[1]); r[2] = f2bf(a[2]); r[3] = f2bf(a[3]);
    r[4] = f2bf(b[0]); r[5] = f2bf(b[1]); r[6] = f2bf(b[2]); r[7] = f2bf(b[3]);
    return r;
}
__device__ inline short8 load_cvt8(const float* __restrict__ p) {
    const f32x4* v = (const f32x4*)p;
    f32x4 a = v[0], b = v[1];
    return cvtf8(a, b);
}

// ---------------------------------------------------------------------------
// Kernel 0: convert all weights to bf16 MFMA B-fragment order in workspace.
// grid = 26 x 256 = 6656 entries, one 16B fragment row per thread.
// ---------------------------------------------------------------------------
__global__ __launch_bounds__(256) void k_prep(
    const float* __restrict__ w_in, const float* __restrict__ w_q,
    const float* __restrict__ w_k, const float* __restrict__ w_v,
    const float* __restrict__ ga_w1, const float* __restrict__ ga_w2,
    const float* __restrict__ w_out, short* __restrict__ wbuf)
{
    int gid = blockIdx.x * 256 + threadIdx.x;
    if (gid >= NFRAG_ENT) return;
    if (gid < 2048) {                               // w_in [64][256]
        int e = gid, f = e >> 6, ln = e & 63;
        int nt = f & 3, ks = f >> 2;
        int row = nt * 16 + (ln & 15), col = ks * 32 + (ln >> 4) * 8;
        *(short8*)&wbuf[(size_t)gid * 8] = load_cvt8(w_in + (size_t)row * INC + col);
    } else if (gid < 4608) {                        // five [64][64] matrices
        int seg = (gid - 2048) >> 9;
        int e = (gid - 2048) & 511;
        const float* m = seg == 0 ? w_q : seg == 1 ? w_k : seg == 2 ? w_v
                       : seg == 3 ? ga_w1 : ga_w2;
        int f = e >> 6, ln = e & 63;
        int nt = f & 3, ks = f >> 2;
        int row = nt * 16 + (ln & 15), col = ks * 32 + (ln >> 4) * 8;
        *(short8*)&wbuf[(size_t)gid * 8] = load_cvt8(m + (size_t)row * MID + col);
    } else {                                        // w_out [256][64]
        int e = gid - 4608, f = e >> 6, ln = e & 63;
        int nt = f >> 1, ks = f & 1;
        int row = nt * 16 + (ln & 15), col = ks * 32 + (ln >> 4) * 8;
        *(short8*)&wbuf[(size_t)gid * 8] = load_cvt8(w_out + (size_t)row * MID + col);
    }
}

// ---------------------------------------------------------------------------
// Kernel 1: xx = feats @ w_in.T ; q/k/v = xx @ w_{q,k,v}.T + b
// block = 256 (4 waves), wave = 2 x 16 rows; grid = 512. LDS 65 KB -> 2 blk/CU.
// ---------------------------------------------------------------------------
__global__ __launch_bounds__(256, 2) void k_qkv(
    const float* __restrict__ feats, const short* __restrict__ wfrag,
    const float* __restrict__ b_q, const float* __restrict__ b_k,
    const float* __restrict__ b_v,
    short* __restrict__ q_out, short* __restrict__ k_out, short* __restrict__ v_out)
{
    __shared__ __align__(16) short WIN[2048 * 8];     // 32 KB
    __shared__ __align__(16) short BW[1536 * 8];      // 24 KB: wq|wk|wv
    __shared__ __align__(16) short XL[4][16 * WSTR];  // 9.2 KB
    const int tid = threadIdx.x;
    const int wave = tid >> 6, lane = tid & 63;
    const int l15 = lane & 15, quad = lane >> 4;

    #pragma unroll
    for (int rep = 0; rep < 8; rep++) {
        int e = rep * 256 + tid;
        *(short8*)&WIN[(size_t)e * 8] = *(const short8*)&wfrag[WIN_S + (size_t)e * 8];
    }
    #pragma unroll
    for (int rep = 0; rep < 6; rep++) {
        int e = rep * 256 + tid;                      // 1536 entries: wq|wk|wv contiguous
        *(short8*)&BW[(size_t)e * 8] = *(const short8*)&wfrag[WQ_S + (size_t)e * 8];
    }
    __syncthreads();

    float biasq[4], biask[4], biasv[4];
    #pragma unroll
    for (int nt = 0; nt < 4; nt++) {
        biasq[nt] = b_q[nt * 16 + l15];
        biask[nt] = b_k[nt * 16 + l15];
        biasv[nt] = b_v[nt * 16 + l15];
    }

    const int rb0 = (blockIdx.x * 4 + wave) * 32;
    #pragma unroll 1
    for (int rt = 0; rt < 2; rt++) {
        const int rb = rb0 + rt * 16;

        f32x4 acc[4];
        #pragma unroll
        for (int nt = 0; nt < 4; nt++) acc[nt] = (f32x4){0.f, 0.f, 0.f, 0.f};
        const float* arow = feats + (size_t)(rb + l15) * INC + quad * 8;
        #pragma unroll
        for (int ks = 0; ks < 8; ks++) {
            short8 a = load_cvt8(arow + ks * 32);
            #pragma unroll
            for (int nt = 0; nt < 4; nt++) {
                short8 b = *(const short8*)&WIN[(size_t)((ks * 4 + nt) * 64 + lane) * 8];
                acc[nt] = MFMA(a, b, acc[nt]);
            }
        }
        #pragma unroll
        for (int nt = 0; nt < 4; nt++)
            #pragma unroll
            for (int r = 0; r < 4; r++)
                XL[wave][(quad * 4 + r) * WSTR + nt * 16 + l15] = f2bf(acc[nt][r]);

        short8 a0 = *(const short8*)&XL[wave][l15 * WSTR + quad * 8];
        short8 a1 = *(const short8*)&XL[wave][l15 * WSTR + 32 + quad * 8];

        // Q
        #pragma unroll
        for (int nt = 0; nt < 4; nt++) {
            short8 b0 = *(const short8*)&BW[(size_t)((nt) * 64 + lane) * 8];
            short8 b1 = *(const short8*)&BW[(size_t)((4 + nt) * 64 + lane) * 8];
            f32x4 c = (f32x4){0.f, 0.f, 0.f, 0.f};
            c = MFMA(a0, b0, c); c = MFMA(a1, b1, c);
            #pragma unroll
            for (int r = 0; r < 4; r++)
                q_out[(size_t)(rb + quad * 4 + r) * MID + nt * 16 + l15] = f2bf(c[r] + biasq[nt]);
        }
        // K
        #pragma unroll
        for (int nt = 0; nt < 4; nt++) {
            short8 b0 = *(const short8*)&BW[(size_t)((8 + nt) * 64 + lane) * 8];
            short8 b1 = *(const short8*)&BW[(size_t)((12 + nt) * 64 + lane) * 8];
            f32x4 c = (f32x4){0.f, 0.f, 0.f, 0.f};
            c = MFMA(a0, b0, c); c = MFMA(a1, b1, c);
            #pragma unroll
            for (int r = 0; r < 4; r++)
                k_out[(size_t)(rb + quad * 4 + r) * MID + nt * 16 + l15] = f2bf(c[r] + biask[nt]);
        }
        // V
        #pragma unroll
        for (int nt = 0; nt < 4; nt++) {
            short8 b0 = *(const short8*)&BW[(size_t)((16 + nt) * 64 + lane) * 8];
            short8 b1 = *(const short8*)&BW[(size_t)((20 + nt) * 64 + lane) * 8];
            f32x4 c = (f32x4){0.f, 0.f, 0.f, 0.f};
            c = MFMA(a0, b0, c); c = MFMA(a1, b1, c);
            #pragma unroll
            for (int r = 0; r < 4; r++)
                v_out[(size_t)(rb + quad * 4 + r) * MID + nt * 16 + l15] = f2bf(c[r] + biasv[nt]);
        }
    }
}

// ---------------------------------------------------------------------------
// Kernel 2: per-point attention. block = 256 (4 waves), 4 points/wave
// sequential; grid = 4096. LDS ~28 KB; VGPR cap 128 (no spills).
// ---------------------------------------------------------------------------
__global__ __launch_bounds__(256, 4) void k_attn(
    const float* __restrict__ pos, const int* __restrict__ idx,
    const unsigned short* __restrict__ q_bf, const unsigned short* __restrict__ k_bf,
    const unsigned short* __restrict__ v_bf, const short* __restrict__ wfrag,
    const float* __restrict__ pe_w1, const float* __restrict__ pe_b1,
    const float* __restrict__ pe_g1, const float* __restrict__ pe_be1,
    const float* __restrict__ pe_m1, const float* __restrict__ pe_v1,
    const float* __restrict__ pe_w2, const float* __restrict__ pe_b2,
    const float* __restrict__ pe_g2, const float* __restrict__ pe_be2,
    const float* __restrict__ pe_m2, const float* __restrict__ pe_v2,
    const float* __restrict__ ga_b1, const float* __restrict__ ga_g1,
    const float* __restrict__ ga_be1, const float* __restrict__ ga_m1,
    const float* __restrict__ ga_v1,
    const float* __restrict__ ga_b2, const float* __restrict__ ga_g2,
    const float* __restrict__ ga_be2, const float* __restrict__ ga_m2,
    const float* __restrict__ ga_v2,
    short* __restrict__ om_bf)
{
    __shared__ __align__(16) short BW[1024 * 8];      // 16 KB: ga_w1|ga_w2
    __shared__ __align__(16) short Wb[4][16 * WSTR];  // 9.2 KB
    __shared__ float GA[4][64];                       // folded BN (1 KB)
    __shared__ float PS[4][16 * 4];                   // PE1 per neighbor (1 KB)
    __shared__ int   JI[4][16];

    const int tid = threadIdx.x;
    const int wave = tid >> 6, lane = tid & 63;
    const int l15 = lane & 15, quad = lane >> 4;

    #pragma unroll
    for (int rep = 0; rep < 4; rep++) {
        int e = rep * 256 + tid;                      // 1024 entries: ga1|ga2 contiguous
        *(short8*)&BW[(size_t)e * 8] = *(const short8*)&wfrag[GA1_S + (size_t)e * 8];
    }
    if (tid < 64) {
        float g1 = ga_g1[tid] * rsqrtf(ga_v1[tid] + 1e-5f);
        GA[0][tid] = g1;
        GA[1][tid] = (ga_b1[tid] - ga_m1[tid]) * g1 + ga_be1[tid];
        float g2 = ga_g2[tid] * rsqrtf(ga_v2[tid] + 1e-5f);
        GA[2][tid] = g2;
        GA[3][tid] = (ga_b2[tid] - ga_m2[tid]) * g2 + ga_be2[tid];
    }
    __syncthreads();

    // per-lane channel params for pos_enc layer 2
    float w20 = pe_w2[lane * 3 + 0], w21 = pe_w2[lane * 3 + 1], w22 = pe_w2[lane * 3 + 2];
    float s2  = pe_g2[lane] * rsqrtf(pe_v2[lane] + 1e-5f);
    float sh2 = (pe_b2[lane] - pe_m2[lane]) * s2 + pe_be2[lane];

    // PE1 folded params (wave-uniform scalars)
    float pw00, pw01, pw02, pw03, pw10, pw11, pw12, pw13, pw20, pw21, pw22, pw23;
    {
        float s0 = pe_g1[0] * rsqrtf(pe_v1[0] + 1e-5f);
        float s1 = pe_g1[1] * rsqrtf(pe_v1[1] + 1e-5f);
        float sc = pe_g1[2] * rsqrtf(pe_v1[2] + 1e-5f);
        pw00 = pe_w1[0] * s0; pw01 = pe_w1[1] * s0; pw02 = pe_w1[2] * s0;
        pw03 = (pe_b1[0] - pe_m1[0]) * s0 + pe_be1[0];
        pw10 = pe_w1[3] * s1; pw11 = pe_w1[4] * s1; pw12 = pe_w1[5] * s1;
        pw13 = (pe_b1[1] - pe_m1[1]) * s1 + pe_be1[1];
        pw20 = pe_w1[6] * sc; pw21 = pe_w1[7] * sc; pw22 = pe_w1[8] * sc;
        pw23 = (pe_b1[2] - pe_m1[2]) * sc + pe_be1[2];
    }

    #pragma unroll 1
    for (int it = 0; it < 4; it++) {
        const int n = blockIdx.x * 16 + it * 4 + wave;

        if (lane < 16) {
            int m = idx[(size_t)n * KNB + lane];
            JI[wave][lane] = m;
            float px = pos[(size_t)m * 3 + 0];
            float py = pos[(size_t)m * 3 + 1];
            float pz = pos[(size_t)m * 3 + 2];
            PS[wave][lane * 4 + 0] = fmaxf(px * pw00 + py * pw01 + pz * pw02 + pw03, 0.f);
            PS[wave][lane * 4 + 1] = fmaxf(px * pw10 + py * pw11 + pz * pw12 + pw13, 0.f);
            PS[wave][lane * 4 + 2] = fmaxf(px * pw20 + py * pw21 + pz * pw22 + pw23, 0.f);
        }
        float qv = bf2f(q_bf[(size_t)n * MID + lane]);

        // gather all 16 k rows (loads stay in flight), then build w = xk - q + p
        unsigned short kr[KNB];
        #pragma unroll
        for (int j = 0; j < KNB; j++)
            kr[j] = k_bf[(size_t)JI[wave][j] * MID + lane];
        #pragma unroll
        for (int j = 0; j < KNB; j++) {
            float p0 = PS[wave][j * 4 + 0], p1 = PS[wave][j * 4 + 1], p2 = PS[wave][j * 4 + 2];
            float p = fmaxf((p0 * w20 + p1 * w21 + p2 * w22) * s2 + sh2, 0.f);
            Wb[wave][j * WSTR + lane] = f2bf(bf2f(kr[j]) - qv + p);
        }

        // mlp_gamma layer 1 (BN folded params from LDS)
        short8 a0 = *(const short8*)&Wb[wave][l15 * WSTR + quad * 8];
        short8 a1 = *(const short8*)&Wb[wave][l15 * WSTR + 32 + quad * 8];
        #pragma unroll
        for (int nt = 0; nt < 4; nt++) {
            short8 b0 = *(const short8*)&BW[(size_t)((nt) * 64 + lane) * 8];
            short8 b1 = *(const short8*)&BW[(size_t)((4 + nt) * 64 + lane) * 8];
            f32x4 c = (f32x4){0.f, 0.f, 0.f, 0.f};
            c = MFMA(a0, b0, c); c = MFMA(a1, b1, c);
            float gs = GA[0][nt * 16 + l15], gh = GA[1][nt * 16 + l15];
            #pragma unroll
            for (int r = 0; r < 4; r++)
                Wb[wave][(quad * 4 + r) * WSTR + nt * 16 + l15] =
                    f2bf(fmaxf(c[r] * gs + gh, 0.f));
        }

        // mlp_gamma layer 2
        short8 c0 = *(const short8*)&Wb[wave][l15 * WSTR + quad * 8];
        short8 c1 = *(const short8*)&Wb[wave][l15 * WSTR + 32 + quad * 8];
        float sm[4][4];
        #pragma unroll
        for (int nt = 0; nt < 4; nt++) {
            short8 b0 = *(const short8*)&BW[(size_t)((8 + nt) * 64 + lane) * 8];
            short8 b1 = *(const short8*)&BW[(size_t)((12 + nt) * 64 + lane) * 8];
            f32x4 c = (f32x4){0.f, 0.f, 0.f, 0.f};
            c = MFMA(c0, b0, c); c = MFMA(c1, b1, c);
            float gs = GA[2][nt * 16 + l15], gh = GA[3][nt * 16 + l15];
            #pragma unroll
            for (int r = 0; r < 4; r++)
                sm[nt][r] = fmaxf(c[r] * gs + gh, 0.f);
        }

        // softmax over 16 neighbors per channel; weights back into Wb (bf16)
        #pragma unroll
        for (int nt = 0; nt < 4; nt++) {
            float mx = fmaxf(fmaxf(sm[nt][0], sm[nt][1]), fmaxf(sm[nt][2], sm[nt][3]));
            mx = fmaxf(mx, __shfl_xor(mx, 16));
            mx = fmaxf(mx, __shfl_xor(mx, 32));
            float e0 = __expf(sm[nt][0] - mx), e1 = __expf(sm[nt][1] - mx);
            float e2 = __expf(sm[nt][2] - mx), e3 = __expf(sm[nt][3] - mx);
            float s = e0 + e1 + e2 + e3;
            s += __shfl_xor(s, 16);
            s += __shfl_xor(s, 32);
            float inv = 1.0f / s;
            Wb[wave][(quad * 4 + 0) * WSTR + nt * 16 + l15] = f2bf(e0 * inv);
            Wb[wave][(quad * 4 + 1) * WSTR + nt * 16 + l15] = f2bf(e1 * inv);
            Wb[wave][(quad * 4 + 2) * WSTR + nt * 16 + l15] = f2bf(e2 * inv);
            Wb[wave][(quad * 4 + 3) * WSTR + nt * 16 + l15] = f2bf(e3 * inv);
        }

        // weighted sum: gather v AFTER softmax (short live range), p recomputed
        unsigned short vr[KNB];
        #pragma unroll
        for (int j = 0; j < KNB; j++)
            vr[j] = v_bf[(size_t)JI[wave][j] * MID + lane];
        float oacc = 0.f;
        #pragma unroll
        for (int j = 0; j < KNB; j++) {
            float p0 = PS[wave][j * 4 + 0], p1 = PS[wave][j * 4 + 1], p2 = PS[wave][j * 4 + 2];
            float p = fmaxf((p0 * w20 + p1 * w21 + p2 * w22) * s2 + sh2, 0.f);
            oacc += (bf2f(vr[j]) + p) * bf2f((unsigned short)Wb[wave][j * WSTR + lane]);
        }
        om_bf[(size_t)n * MID + lane] = f2bf(oacc);
    }
}

// ---------------------------------------------------------------------------
// Kernel 3: out = out_mid @ w_out.T + feats
// block = 256 (4 waves), wave = 2 x 16 rows; grid = 512. w_out LDS 32 KB.
// ---------------------------------------------------------------------------
__global__ __launch_bounds__(256, 4) void k_out(
    const unsigned short* __restrict__ om_bf, const short* __restrict__ wfrag,
    const float* __restrict__ feats, float* __restrict__ out)
{
    __shared__ __align__(16) short BW[2048 * 8];      // 32 KB
    const int tid = threadIdx.x;
    const int wave = tid >> 6, lane = tid & 63;
    const int l15 = lane & 15, quad = lane >> 4;

    #pragma unroll
    for (int rep = 0; rep < 8; rep++) {
        int e = rep * 256 + tid;
        *(short8*)&BW[(size_t)e * 8] = *(const short8*)&wfrag[WOUT_S + (size_t)e * 8];
    }
    __syncthreads();

    const int rb0 = (blockIdx.x * 4 + wave) * 32;
    #pragma unroll 1
    for (int rt = 0; rt < 2; rt++) {
        const int rb = rb0 + rt * 16;
        short8 A0 = *(const short8*)(om_bf + (size_t)(rb + l15) * MID + quad * 8);
        short8 A1 = *(const short8*)(om_bf + (size_t)(rb + l15) * MID + 32 + quad * 8);

        #pragma unroll 4
        for (int nt = 0; nt < 16; nt++) {
            short8 b0 = *(const short8*)&BW[(size_t)((nt * 2 + 0) * 64 + lane) * 8];
            short8 b1 = *(const short8*)&BW[(size_t)((nt * 2 + 1) * 64 + lane) * 8];
            f32x4 c = (f32x4){0.f, 0.f, 0.f, 0.f};
            c = MFMA(A0, b0, c);
            c = MFMA(A1, b1, c);
            #pragma unroll
            for (int r = 0; r < 4; r++) {
                size_t off = (size_t)(rb + quad * 4 + r) * INC + nt * 16 + l15;
                out[off] = c[r] + feats[off];
            }
        }
    }
}

extern "C" void kernel_launch(void* const* d_in, const int* in_sizes, int n_in,
                              void* d_out, int out_size, void* d_ws, size_t ws_size,
                              hipStream_t stream)
{
    const float* feats = (const float*)d_in[0];
    const float* pos   = (const float*)d_in[1];
    const int*   idx   = (const int*)d_in[2];
    const float* w_in  = (const float*)d_in[3];
    const float* w_q   = (const float*)d_in[4];
    const float* b_q   = (const float*)d_in[5];
    const float* w_k   = (const float*)d_in[6];
    const float* b_k   = (const float*)d_in[7];
    const float* w_v   = (const float*)d_in[8];
    const float* b_v   = (const float*)d_in[9];
    const float* pe_w1 = (const float*)d_in[10];
    const float* pe_b1 = (const float*)d_in[11];
    const float* pe_g1 = (const float*)d_in[12];
    const float* pe_be1= (const float*)d_in[13];
    const float* pe_m1 = (const float*)d_in[14];
    const float* pe_v1 = (const float*)d_in[15];
    const float* pe_w2 = (const float*)d_in[16];
    const float* pe_b2 = (const float*)d_in[17];
    const float* pe_g2 = (const float*)d_in[18];
    const float* pe_be2= (const float*)d_in[19];
    const float* pe_m2 = (const float*)d_in[20];
    const float* pe_v2 = (const float*)d_in[21];
    const float* ga_w1 = (const float*)d_in[22];
    const float* ga_b1 = (const float*)d_in[23];
    const float* ga_g1 = (const float*)d_in[24];
    const float* ga_be1= (const float*)d_in[25];
    const float* ga_m1 = (const float*)d_in[26];
    const float* ga_v1 = (const float*)d_in[27];
    const float* ga_w2 = (const float*)d_in[28];
    const float* ga_b2 = (const float*)d_in[29];
    const float* ga_g2 = (const float*)d_in[30];
    const float* ga_be2= (const float*)d_in[31];
    const float* ga_m2 = (const float*)d_in[32];
    const float* ga_v2 = (const float*)d_in[33];
    const float* w_out = (const float*)d_in[34];

    char* ws = (char*)d_ws;
    short* q_bf  = (short*)(ws);                            // 8 MB
    short* k_bf  = (short*)(ws + (size_t) 8 * 1024 * 1024); // 8 MB
    short* v_bf  = (short*)(ws + (size_t)16 * 1024 * 1024); // 8 MB
    short* om_bf = (short*)(ws + (size_t)24 * 1024 * 1024); // 8 MB
    short* wbuf  = (short*)(ws + (size_t)32 * 1024 * 1024); // 104 KB frag buffer

    k_prep<<<26, 256, 0, stream>>>(w_in, w_q, w_k, w_v, ga_w1, ga_w2, w_out, wbuf);
    k_qkv<<<NPTS / 128, 256, 0, stream>>>(feats, wbuf, b_q, b_k, b_v, q_bf, k_bf, v_bf);
    k_attn<<<NPTS / 16, 256, 0, stream>>>(pos, idx,
                                          (const unsigned short*)q_bf,
                                          (const unsigned short*)k_bf, (const unsigned short*)v_bf,
                                          wbuf,
                                          pe_w1, pe_b1, pe_g1, pe_be1, pe_m1, pe_v1,
                                          pe_w2, pe_b2, pe_g2, pe_be2, pe_m2, pe_v2,
                                          ga_b1, ga_g1, ga_be1, ga_m1, ga_v1,
                                          ga_b2, ga_g2, ga_be2, ga_m2, ga_v2,
                                          om_bf);
    k_out<<<NPTS / 128, 256, 0, stream>>>((const unsigned short*)om_bf, wbuf, feats, (float*)d_out);
}

// Round 6
// 352.195 us; speedup vs baseline: 1.6091x; 1.6091x over previous
//
#include <hip/hip_runtime.h>

#define NPTS 65536
#define INC  256
#define MID  64
#define KNB  16
#define WSTR 72   // padded LDS row stride (shorts)

// fragment-buffer offsets in shorts (workspace, written by k_prep)
#define WIN_S   0        // w_in   2048 entries
#define WQ_S    16384    // w_q     512
#define WK_S    20480    // w_k     512
#define WV_S    24576    // w_v     512
#define GA1_S   28672    // ga_w1   512
#define GA2_S   32768    // ga_w2   512
#define WOUT_S  36864    // w_out  2048
#define NFRAG_ENT 6656

typedef __attribute__((ext_vector_type(8))) short short8;
typedef __attribute__((ext_vector_type(4))) float f32x4;

#define MFMA(a, b, c) __builtin_amdgcn_mfma_f32_16x16x32_bf16((a), (b), (c), 0, 0, 0)

__device__ inline short f2bf(float f) {
    unsigned int u = __builtin_bit_cast(unsigned int, f);
    unsigned int r = (u + 0x7fffu + ((u >> 16) & 1u)) >> 16;
    return (short)r;
}
__device__ inline float bf2f(unsigned short s) {
    unsigned int u = ((unsigned int)s) << 16;
    return __builtin_bit_cast(float, u);
}
__device__ inline short8 cvtf8(f32x4 a, f32x4 b) {
    short8 r;
    r[0] = f2bf(a[0]); r[1] = f2bf(a[1]); r[2] = f2bf(a[2]); r[3] = f2bf(a[3]);
    r[4] = f2bf(b[0]); r[5] = f2bf(b[1]); r[6] = f2bf(b[2]); r[7] = f2bf(b[3]);
    return r;
}
__device__ inline short8 load_cvt8(const float* __restrict__ p) {
    const f32x4* v = (const f32x4*)p;
    f32x4 a = v[0], b = v[1];
    return cvtf8(a, b);
}

// ---------------------------------------------------------------------------
// Kernel 0: convert all weights to bf16 MFMA B-fragment order in workspace.
// ---------------------------------------------------------------------------
__global__ __launch_bounds__(256) void k_prep(
    const float* __restrict__ w_in, const float* __restrict__ w_q,
    const float* __restrict__ w_k, const float* __restrict__ w_v,
    const float* __restrict__ ga_w1, const float* __restrict__ ga_w2,
    const float* __restrict__ w_out, short* __restrict__ wbuf)
{
    int gid = blockIdx.x * 256 + threadIdx.x;
    if (gid >= NFRAG_ENT) return;
    if (gid < 2048) {                               // w_in [64][256]
        int e = gid, f = e >> 6, ln = e & 63;
        int nt = f & 3, ks = f >> 2;
        int row = nt * 16 + (ln & 15), col = ks * 32 + (ln >> 4) * 8;
        *(short8*)&wbuf[(size_t)gid * 8] = load_cvt8(w_in + (size_t)row * INC + col);
    } else if (gid < 4608) {                        // five [64][64] matrices
        int seg = (gid - 2048) >> 9;
        int e = (gid - 2048) & 511;
        const float* m = seg == 0 ? w_q : seg == 1 ? w_k : seg == 2 ? w_v
                       : seg == 3 ? ga_w1 : ga_w2;
        int f = e >> 6, ln = e & 63;
        int nt = f & 3, ks = f >> 2;
        int row = nt * 16 + (ln & 15), col = ks * 32 + (ln >> 4) * 8;
        *(short8*)&wbuf[(size_t)gid * 8] = load_cvt8(m + (size_t)row * MID + col);
    } else {                                        // w_out [256][64]
        int e = gid - 4608, f = e >> 6, ln = e & 63;
        int nt = f >> 1, ks = f & 1;
        int row = nt * 16 + (ln & 15), col = ks * 32 + (ln >> 4) * 8;
        *(short8*)&wbuf[(size_t)gid * 8] = load_cvt8(w_out + (size_t)row * MID + col);
    }
}

// ---------------------------------------------------------------------------
// Kernel 1: xx = feats @ w_in.T ; q/k/v = xx @ w_{q,k,v}.T + b
// block = 256 (4 waves), 1 row-tile/wave; grid = 1024. B-frags read directly
// from global wbuf (coalesced 16 B/lane, L2-hot). No barriers. LDS = 9 KB.
// ---------------------------------------------------------------------------
__global__ __launch_bounds__(256) void k_qkv(
    const float* __restrict__ feats, const short* __restrict__ wfrag,
    const float* __restrict__ b_q, const float* __restrict__ b_k,
    const float* __restrict__ b_v,
    short* __restrict__ q_out, short* __restrict__ k_out, short* __restrict__ v_out)
{
    __shared__ __align__(16) short XL[4][16 * WSTR];  // 9.2 KB, wave-private
    const int tid = threadIdx.x;
    const int wave = tid >> 6, lane = tid & 63;
    const int l15 = lane & 15, quad = lane >> 4;
    const int rb = (blockIdx.x * 4 + wave) * 16;

    // xx = feats @ w_in.T
    f32x4 acc[4];
    #pragma unroll
    for (int nt = 0; nt < 4; nt++) acc[nt] = (f32x4){0.f, 0.f, 0.f, 0.f};
    const float* arow = feats + (size_t)(rb + l15) * INC + quad * 8;
    #pragma unroll
    for (int ks = 0; ks < 8; ks++) {
        short8 a = load_cvt8(arow + ks * 32);
        #pragma unroll
        for (int nt = 0; nt < 4; nt++) {
            short8 b = *(const short8*)&wfrag[WIN_S + (size_t)((ks * 4 + nt) * 64 + lane) * 8];
            acc[nt] = MFMA(a, b, acc[nt]);
        }
    }
    #pragma unroll
    for (int nt = 0; nt < 4; nt++)
        #pragma unroll
        for (int r = 0; r < 4; r++)
            XL[wave][(quad * 4 + r) * WSTR + nt * 16 + l15] = f2bf(acc[nt][r]);

    short8 a0 = *(const short8*)&XL[wave][l15 * WSTR + quad * 8];
    short8 a1 = *(const short8*)&XL[wave][l15 * WSTR + 32 + quad * 8];

    // Q
    #pragma unroll
    for (int nt = 0; nt < 4; nt++) {
        short8 b0 = *(const short8*)&wfrag[WQ_S + (size_t)((nt) * 64 + lane) * 8];
        short8 b1 = *(const short8*)&wfrag[WQ_S + (size_t)((4 + nt) * 64 + lane) * 8];
        f32x4 c = (f32x4){0.f, 0.f, 0.f, 0.f};
        c = MFMA(a0, b0, c); c = MFMA(a1, b1, c);
        float bias = b_q[nt * 16 + l15];
        #pragma unroll
        for (int r = 0; r < 4; r++)
            q_out[(size_t)(rb + quad * 4 + r) * MID + nt * 16 + l15] = f2bf(c[r] + bias);
    }
    // K
    #pragma unroll
    for (int nt = 0; nt < 4; nt++) {
        short8 b0 = *(const short8*)&wfrag[WK_S + (size_t)((nt) * 64 + lane) * 8];
        short8 b1 = *(const short8*)&wfrag[WK_S + (size_t)((4 + nt) * 64 + lane) * 8];
        f32x4 c = (f32x4){0.f, 0.f, 0.f, 0.f};
        c = MFMA(a0, b0, c); c = MFMA(a1, b1, c);
        float bias = b_k[nt * 16 + l15];
        #pragma unroll
        for (int r = 0; r < 4; r++)
            k_out[(size_t)(rb + quad * 4 + r) * MID + nt * 16 + l15] = f2bf(c[r] + bias);
    }
    // V
    #pragma unroll
    for (int nt = 0; nt < 4; nt++) {
        short8 b0 = *(const short8*)&wfrag[WV_S + (size_t)((nt) * 64 + lane) * 8];
        short8 b1 = *(const short8*)&wfrag[WV_S + (size_t)((4 + nt) * 64 + lane) * 8];
        f32x4 c = (f32x4){0.f, 0.f, 0.f, 0.f};
        c = MFMA(a0, b0, c); c = MFMA(a1, b1, c);
        float bias = b_v[nt * 16 + l15];
        #pragma unroll
        for (int r = 0; r < 4; r++)
            v_out[(size_t)(rb + quad * 4 + r) * MID + nt * 16 + l15] = f2bf(c[r] + bias);
    }
}

// ---------------------------------------------------------------------------
// Kernel 2: per-point attention. block = 256 (4 waves), 1 pt/wave x 4 iters;
// grid = 4096. NO launch-bounds occupancy floor (spill avoidance). LDS 27 KB.
// ---------------------------------------------------------------------------
__global__ __launch_bounds__(256) void k_attn(
    const float* __restrict__ pos, const int* __restrict__ idx,
    const unsigned short* __restrict__ q_bf, const unsigned short* __restrict__ k_bf,
    const unsigned short* __restrict__ v_bf, const short* __restrict__ wfrag,
    const float* __restrict__ pe_w1, const float* __restrict__ pe_b1,
    const float* __restrict__ pe_g1, const float* __restrict__ pe_be1,
    const float* __restrict__ pe_m1, const float* __restrict__ pe_v1,
    const float* __restrict__ pe_w2, const float* __restrict__ pe_b2,
    const float* __restrict__ pe_g2, const float* __restrict__ pe_be2,
    const float* __restrict__ pe_m2, const float* __restrict__ pe_v2,
    const float* __restrict__ ga_b1, const float* __restrict__ ga_g1,
    const float* __restrict__ ga_be1, const float* __restrict__ ga_m1,
    const float* __restrict__ ga_v1,
    const float* __restrict__ ga_b2, const float* __restrict__ ga_g2,
    const float* __restrict__ ga_be2, const float* __restrict__ ga_m2,
    const float* __restrict__ ga_v2,
    short* __restrict__ om_bf)
{
    __shared__ __align__(16) short BW[1024 * 8];      // 16 KB: ga_w1|ga_w2
    __shared__ __align__(16) short Wb[4][16 * WSTR];  // 9.2 KB
    __shared__ float GA[4][64];                       // folded BN (1 KB)
    __shared__ float PS[4][16 * 4];                   // PE1 per neighbor (1 KB)
    __shared__ int   JI[4][16];

    const int tid = threadIdx.x;
    const int wave = tid >> 6, lane = tid & 63;
    const int l15 = lane & 15, quad = lane >> 4;

    #pragma unroll
    for (int rep = 0; rep < 4; rep++) {
        int e = rep * 256 + tid;                      // 1024 entries: ga1|ga2 contiguous
        *(short8*)&BW[(size_t)e * 8] = *(const short8*)&wfrag[GA1_S + (size_t)e * 8];
    }
    if (tid < 64) {
        float g1 = ga_g1[tid] * rsqrtf(ga_v1[tid] + 1e-5f);
        GA[0][tid] = g1;
        GA[1][tid] = (ga_b1[tid] - ga_m1[tid]) * g1 + ga_be1[tid];
        float g2 = ga_g2[tid] * rsqrtf(ga_v2[tid] + 1e-5f);
        GA[2][tid] = g2;
        GA[3][tid] = (ga_b2[tid] - ga_m2[tid]) * g2 + ga_be2[tid];
    }
    __syncthreads();

    // per-lane channel params for pos_enc layer 2
    float w20 = pe_w2[lane * 3 + 0], w21 = pe_w2[lane * 3 + 1], w22 = pe_w2[lane * 3 + 2];
    float s2  = pe_g2[lane] * rsqrtf(pe_v2[lane] + 1e-5f);
    float sh2 = (pe_b2[lane] - pe_m2[lane]) * s2 + pe_be2[lane];

    // PE1 folded params (wave-uniform scalars)
    float pw00, pw01, pw02, pw03, pw10, pw11, pw12, pw13, pw20, pw21, pw22, pw23;
    {
        float s0 = pe_g1[0] * rsqrtf(pe_v1[0] + 1e-5f);
        float s1 = pe_g1[1] * rsqrtf(pe_v1[1] + 1e-5f);
        float sc = pe_g1[2] * rsqrtf(pe_v1[2] + 1e-5f);
        pw00 = pe_w1[0] * s0; pw01 = pe_w1[1] * s0; pw02 = pe_w1[2] * s0;
        pw03 = (pe_b1[0] - pe_m1[0]) * s0 + pe_be1[0];
        pw10 = pe_w1[3] * s1; pw11 = pe_w1[4] * s1; pw12 = pe_w1[5] * s1;
        pw13 = (pe_b1[1] - pe_m1[1]) * s1 + pe_be1[1];
        pw20 = pe_w1[6] * sc; pw21 = pe_w1[7] * sc; pw22 = pe_w1[8] * sc;
        pw23 = (pe_b1[2] - pe_m1[2]) * sc + pe_be1[2];
    }

    #pragma unroll 1
    for (int it = 0; it < 4; it++) {
        const int n = blockIdx.x * 16 + it * 4 + wave;

        if (lane < 16) {
            int m = idx[(size_t)n * KNB + lane];
            JI[wave][lane] = m;
            float px = pos[(size_t)m * 3 + 0];
            float py = pos[(size_t)m * 3 + 1];
            float pz = pos[(size_t)m * 3 + 2];
            PS[wave][lane * 4 + 0] = fmaxf(px * pw00 + py * pw01 + pz * pw02 + pw03, 0.f);
            PS[wave][lane * 4 + 1] = fmaxf(px * pw10 + py * pw11 + pz * pw12 + pw13, 0.f);
            PS[wave][lane * 4 + 2] = fmaxf(px * pw20 + py * pw21 + pz * pw22 + pw23, 0.f);
        }
        float qv = bf2f(q_bf[(size_t)n * MID + lane]);

        // gather all 16 k rows (loads stay in flight), build w = xk - q + p
        unsigned short kr[KNB];
        #pragma unroll
        for (int j = 0; j < KNB; j++)
            kr[j] = k_bf[(size_t)JI[wave][j] * MID + lane];
        #pragma unroll
        for (int j = 0; j < KNB; j++) {
            float p0 = PS[wave][j * 4 + 0], p1 = PS[wave][j * 4 + 1], p2 = PS[wave][j * 4 + 2];
            float p = fmaxf((p0 * w20 + p1 * w21 + p2 * w22) * s2 + sh2, 0.f);
            Wb[wave][j * WSTR + lane] = f2bf(bf2f(kr[j]) - qv + p);
        }

        // mlp_gamma layer 1
        short8 a0 = *(const short8*)&Wb[wave][l15 * WSTR + quad * 8];
        short8 a1 = *(const short8*)&Wb[wave][l15 * WSTR + 32 + quad * 8];
        #pragma unroll
        for (int nt = 0; nt < 4; nt++) {
            short8 b0 = *(const short8*)&BW[(size_t)((nt) * 64 + lane) * 8];
            short8 b1 = *(const short8*)&BW[(size_t)((4 + nt) * 64 + lane) * 8];
            f32x4 c = (f32x4){0.f, 0.f, 0.f, 0.f};
            c = MFMA(a0, b0, c); c = MFMA(a1, b1, c);
            float gs = GA[0][nt * 16 + l15], gh = GA[1][nt * 16 + l15];
            #pragma unroll
            for (int r = 0; r < 4; r++)
                Wb[wave][(quad * 4 + r) * WSTR + nt * 16 + l15] =
                    f2bf(fmaxf(c[r] * gs + gh, 0.f));
        }

        // mlp_gamma layer 2
        short8 c0 = *(const short8*)&Wb[wave][l15 * WSTR + quad * 8];
        short8 c1 = *(const short8*)&Wb[wave][l15 * WSTR + 32 + quad * 8];
        float sm[4][4];
        #pragma unroll
        for (int nt = 0; nt < 4; nt++) {
            short8 b0 = *(const short8*)&BW[(size_t)((8 + nt) * 64 + lane) * 8];
            short8 b1 = *(const short8*)&BW[(size_t)((12 + nt) * 64 + lane) * 8];
            f32x4 c = (f32x4){0.f, 0.f, 0.f, 0.f};
            c = MFMA(c0, b0, c); c = MFMA(c1, b1, c);
            float gs = GA[2][nt * 16 + l15], gh = GA[3][nt * 16 + l15];
            #pragma unroll
            for (int r = 0; r < 4; r++)
                sm[nt][r] = fmaxf(c[r] * gs + gh, 0.f);
        }

        // softmax over 16 neighbors per channel; weights back into Wb (bf16)
        #pragma unroll
        for (int nt = 0; nt < 4; nt++) {
            float mx = fmaxf(fmaxf(sm[nt][0], sm[nt][1]), fmaxf(sm[nt][2], sm[nt][3]));
            mx = fmaxf(mx, __shfl_xor(mx, 16));
            mx = fmaxf(mx, __shfl_xor(mx, 32));
            float e0 = __expf(sm[nt][0] - mx), e1 = __expf(sm[nt][1] - mx);
            float e2 = __expf(sm[nt][2] - mx), e3 = __expf(sm[nt][3] - mx);
            float s = e0 + e1 + e2 + e3;
            s += __shfl_xor(s, 16);
            s += __shfl_xor(s, 32);
            float inv = 1.0f / s;
            Wb[wave][(quad * 4 + 0) * WSTR + nt * 16 + l15] = f2bf(e0 * inv);
            Wb[wave][(quad * 4 + 1) * WSTR + nt * 16 + l15] = f2bf(e1 * inv);
            Wb[wave][(quad * 4 + 2) * WSTR + nt * 16 + l15] = f2bf(e2 * inv);
            Wb[wave][(quad * 4 + 3) * WSTR + nt * 16 + l15] = f2bf(e3 * inv);
        }

        // weighted sum: gather v AFTER softmax (short live range), p recomputed
        unsigned short vr[KNB];
        #pragma unroll
        for (int j = 0; j < KNB; j++)
            vr[j] = v_bf[(size_t)JI[wave][j] * MID + lane];
        float oacc = 0.f;
        #pragma unroll
        for (int j = 0; j < KNB; j++) {
            float p0 = PS[wave][j * 4 + 0], p1 = PS[wave][j * 4 + 1], p2 = PS[wave][j * 4 + 2];
            float p = fmaxf((p0 * w20 + p1 * w21 + p2 * w22) * s2 + sh2, 0.f);
            oacc += (bf2f(vr[j]) + p) * bf2f((unsigned short)Wb[wave][j * WSTR + lane]);
        }
        om_bf[(size_t)n * MID + lane] = f2bf(oacc);
    }
}

// ---------------------------------------------------------------------------
// Kernel 3: out = out_mid @ w_out.T + feats
// block = 256 (4 waves), 1 row-tile/wave; grid = 1024. NO LDS, no barriers;
// B-frags streamed from global wbuf (coalesced, L2-hot).
// ---------------------------------------------------------------------------
__global__ __launch_bounds__(256) void k_out(
    const unsigned short* __restrict__ om_bf, const short* __restrict__ wfrag,
    const float* __restrict__ feats, float* __restrict__ out)
{
    const int tid = threadIdx.x;
    const int wave = tid >> 6, lane = tid & 63;
    const int l15 = lane & 15, quad = lane >> 4;
    const int rb = (blockIdx.x * 4 + wave) * 16;

    short8 A0 = *(const short8*)(om_bf + (size_t)(rb + l15) * MID + quad * 8);
    short8 A1 = *(const short8*)(om_bf + (size_t)(rb + l15) * MID + 32 + quad * 8);

    #pragma unroll 4
    for (int nt = 0; nt < 16; nt++) {
        short8 b0 = *(const short8*)&wfrag[WOUT_S + (size_t)((nt * 2 + 0) * 64 + lane) * 8];
        short8 b1 = *(const short8*)&wfrag[WOUT_S + (size_t)((nt * 2 + 1) * 64 + lane) * 8];
        f32x4 c = (f32x4){0.f, 0.f, 0.f, 0.f};
        c = MFMA(A0, b0, c);
        c = MFMA(A1, b1, c);
        #pragma unroll
        for (int r = 0; r < 4; r++) {
            size_t off = (size_t)(rb + quad * 4 + r) * INC + nt * 16 + l15;
            out[off] = c[r] + feats[off];
        }
    }
}

extern "C" void kernel_launch(void* const* d_in, const int* in_sizes, int n_in,
                              void* d_out, int out_size, void* d_ws, size_t ws_size,
                              hipStream_t stream)
{
    const float* feats = (const float*)d_in[0];
    const float* pos   = (const float*)d_in[1];
    const int*   idx   = (const int*)d_in[2];
    const float* w_in  = (const float*)d_in[3];
    const float* w_q   = (const float*)d_in[4];
    const float* b_q   = (const float*)d_in[5];
    const float* w_k   = (const float*)d_in[6];
    const float* b_k   = (const float*)d_in[7];
    const float* w_v   = (const float*)d_in[8];
    const float* b_v   = (const float*)d_in[9];
    const float* pe_w1 = (const float*)d_in[10];
    const float* pe_b1 = (const float*)d_in[11];
    const float* pe_g1 = (const float*)d_in[12];
    const float* pe_be1= (const float*)d_in[13];
    const float* pe_m1 = (const float*)d_in[14];
    const float* pe_v1 = (const float*)d_in[15];
    const float* pe_w2 = (const float*)d_in[16];
    const float* pe_b2 = (const float*)d_in[17];
    const float* pe_g2 = (const float*)d_in[18];
    const float* pe_be2= (const float*)d_in[19];
    const float* pe_m2 = (const float*)d_in[20];
    const float* pe_v2 = (const float*)d_in[21];
    const float* ga_w1 = (const float*)d_in[22];
    const float* ga_b1 = (const float*)d_in[23];
    const float* ga_g1 = (const float*)d_in[24];
    const float* ga_be1= (const float*)d_in[25];
    const float* ga_m1 = (const float*)d_in[26];
    const float* ga_v1 = (const float*)d_in[27];
    const float* ga_w2 = (const float*)d_in[28];
    const float* ga_b2 = (const float*)d_in[29];
    const float* ga_g2 = (const float*)d_in[30];
    const float* ga_be2= (const float*)d_in[31];
    const float* ga_m2 = (const float*)d_in[32];
    const float* ga_v2 = (const float*)d_in[33];
    const float* w_out = (const float*)d_in[34];

    char* ws = (char*)d_ws;
    short* q_bf  = (short*)(ws);                            // 8 MB
    short* k_bf  = (short*)(ws + (size_t) 8 * 1024 * 1024); // 8 MB
    short* v_bf  = (short*)(ws + (size_t)16 * 1024 * 1024); // 8 MB
    short* om_bf = (short*)(ws + (size_t)24 * 1024 * 1024); // 8 MB
    short* wbuf  = (short*)(ws + (size_t)32 * 1024 * 1024); // 104 KB frag buffer

    k_prep<<<26, 256, 0, stream>>>(w_in, w_q, w_k, w_v, ga_w1, ga_w2, w_out, wbuf);
    k_qkv<<<NPTS / 64, 256, 0, stream>>>(feats, wbuf, b_q, b_k, b_v, q_bf, k_bf, v_bf);
    k_attn<<<NPTS / 16, 256, 0, stream>>>(pos, idx,
                                          (const unsigned short*)q_bf,
                                          (const unsigned short*)k_bf, (const unsigned short*)v_bf,
                                          wbuf,
                                          pe_w1, pe_b1, pe_g1, pe_be1, pe_m1, pe_v1,
                                          pe_w2, pe_b2, pe_g2, pe_be2, pe_m2, pe_v2,
                                          ga_b1, ga_g1, ga_be1, ga_m1, ga_v1,
                                          ga_b2, ga_g2, ga_be2, ga_m2, ga_v2,
                                          om_bf);
    k_out<<<NPTS / 64, 256, 0, stream>>>((const unsigned short*)om_bf, wbuf, feats, (float*)d_out);
}